// Round 3
// baseline (712.150 us; speedup 1.0000x reference)
//
#include <hip/hip_runtime.h>

// GCN 2-layer: N=100000, F=128 -> H=16 (relu) -> C=40, E=3200000.
// R2 -> R3: replace float-atomic scatters (2 x 167us, atomic-RMW bound at
// ~306 G-atomics/s) with a one-time counting sort by dst (CSR) + two
// gather-aggregate kernels (no float atomics, register accumulation).
//
// Pipeline (fp32):
//  k_zero/k_count : cnt[i] = in-degree (int atomics)
//  k_dinv         : dinv = rsqrt(1+cnt)
//  k_scan1/2/3    : row_ptr = exclusive scan(cnt); cursor = row_ptr copy
//  k_bucket       : src_sorted[atomic cursor[dst[e]]++] = src[e]
//  k_gemm1        : h1 = x@W1
//  k_agg<false>   : agg1[n] = dinv[n]*(sum_{e->n} h1[s]*dinv[s] + dinv[n]*h1[n])
//  k_agg<true>    : same with h = relu(agg1+b1) computed on the fly -> agg2
//  k_out          : out = agg2@W2 + b2

#define N_NODES 100000
#define F_IN    128
#define H_MID   16
#define C_OUT   40
#define N_EDGES 3200000
#define SCAN_B  1024
#define SCAN_G  98          // ceil(100000/1024)

__global__ void k_zero(int* __restrict__ cnt) {
    int i = blockIdx.x * 256 + threadIdx.x;
    if (i < N_NODES) cnt[i] = 0;
}

__global__ void k_count(const int* __restrict__ dst, int* __restrict__ cnt) {
    int e = blockIdx.x * 256 + threadIdx.x;
    if (e < N_EDGES) atomicAdd(&cnt[dst[e]], 1);
}

__global__ void k_dinv(const int* __restrict__ cnt, float* __restrict__ dinv) {
    int i = blockIdx.x * 256 + threadIdx.x;
    if (i < N_NODES) dinv[i] = rsqrtf(1.0f + (float)cnt[i]);   // +1 = self loop
}

// ---- 3-kernel exclusive scan of cnt[100000] -> row_ptr, cursor ----
__global__ void __launch_bounds__(SCAN_B) k_scan1(const int* __restrict__ cnt,
                                                  int* __restrict__ part) {
    __shared__ int s[SCAN_B];
    int i = blockIdx.x * SCAN_B + threadIdx.x;
    s[threadIdx.x] = (i < N_NODES) ? cnt[i] : 0;
    __syncthreads();
    for (int off = SCAN_B / 2; off > 0; off >>= 1) {
        if (threadIdx.x < off) s[threadIdx.x] += s[threadIdx.x + off];
        __syncthreads();
    }
    if (threadIdx.x == 0) part[blockIdx.x] = s[0];
}

__global__ void k_scan2(int* __restrict__ part) {
    if (threadIdx.x == 0) {
        int acc = 0;
        for (int b = 0; b < SCAN_G; ++b) { int v = part[b]; part[b] = acc; acc += v; }
    }
}

__global__ void __launch_bounds__(SCAN_B) k_scan3(const int* __restrict__ cnt,
                                                  const int* __restrict__ part,
                                                  int* __restrict__ row_ptr,
                                                  int* __restrict__ cursor) {
    __shared__ int s[SCAN_B];
    int i = blockIdx.x * SCAN_B + threadIdx.x;
    int v = (i < N_NODES) ? cnt[i] : 0;
    s[threadIdx.x] = v;
    __syncthreads();
    for (int off = 1; off < SCAN_B; off <<= 1) {       // Hillis-Steele inclusive
        int t = (threadIdx.x >= off) ? s[threadIdx.x - off] : 0;
        __syncthreads();
        s[threadIdx.x] += t;
        __syncthreads();
    }
    int excl = s[threadIdx.x] - v + part[blockIdx.x];
    if (i < N_NODES) { row_ptr[i] = excl; cursor[i] = excl; }
    if (i == N_NODES - 1) row_ptr[N_NODES] = N_EDGES;
}

__global__ void k_bucket(const int* __restrict__ src, const int* __restrict__ dst,
                         int* __restrict__ cursor, int* __restrict__ src_sorted) {
    int e = blockIdx.x * 256 + threadIdx.x;
    if (e < N_EDGES) {
        int d = dst[e];
        int pos = atomicAdd(&cursor[d], 1);
        src_sorted[pos] = src[e];
    }
}

// h1 = x@W1 : 16 nodes per block, 256 threads = 16 nodes x 16 features.
__global__ void __launch_bounds__(256) k_gemm1(
    const float* __restrict__ x, const float* __restrict__ W1,
    float* __restrict__ h1) {
    __shared__ float w[F_IN * H_MID];   // 8 KB
    __shared__ float xs[16 * 132];      // padded rows
    int t = threadIdx.x;
    for (int i = t; i < F_IN * H_MID; i += 256) w[i] = W1[i];
    int tile = blockIdx.x;              // 6250 tiles, exact
    const float4* xg = (const float4*)(x + (size_t)tile * 16 * F_IN);
    float4* xs4 = (float4*)xs;          // row stride 33 float4
    for (int i = t; i < 512; i += 256) {
        int r = i >> 5, c4 = i & 31;
        xs4[r * 33 + c4] = xg[r * 32 + c4];
    }
    __syncthreads();
    int node = t >> 4, j = t & 15;
    const float* xr = xs + node * 132;
    float acc = 0.f;
#pragma unroll 8
    for (int k = 0; k < F_IN; ++k) acc += xr[k] * w[k * H_MID + j];
    h1[(size_t)(tile * 16 + node) * H_MID + j] = acc;
}

// One node per wave: 16 lanes = features, 4 edge slots. 4 nodes per block.
template<bool RELU>
__global__ void __launch_bounds__(256) k_agg(
    const int* __restrict__ row_ptr, const int* __restrict__ src_sorted,
    const float* __restrict__ dinv, const float* __restrict__ hin,
    const float* __restrict__ b1, float* __restrict__ aggout) {
    int lane = threadIdx.x & 63;
    int n = blockIdx.x * 4 + (threadIdx.x >> 6);
    int j = lane & 15, sub = lane >> 4;
    float bj = RELU ? b1[j] : 0.f;
    int s0 = row_ptr[n], s1 = row_ptr[n + 1];
    float acc = 0.f;
    for (int e = s0 + sub; e < s1; e += 4) {
        int s = src_sorted[e];
        float v = hin[(size_t)s * H_MID + j];
        if (RELU) v = fmaxf(v + bj, 0.f);
        acc += v * dinv[s];
    }
    acc += __shfl_xor(acc, 16, 64);
    acc += __shfl_xor(acc, 32, 64);
    if (sub == 0) {
        float dn = dinv[n];
        float self = hin[(size_t)n * H_MID + j];
        if (RELU) self = fmaxf(self + bj, 0.f);
        aggout[(size_t)n * H_MID + j] = dn * (acc + dn * self);
    }
}

// out = agg2@W2 + b2 : 16 nodes/block x 40 classes = 640 threads.
__global__ void __launch_bounds__(640) k_out(
    const float* __restrict__ agg2, const float* __restrict__ W2,
    const float* __restrict__ b2, float* __restrict__ out) {
    __shared__ float w2[H_MID * C_OUT];  // 640
    __shared__ float r[16 * 17];         // padded
    int t = threadIdx.x;
    if (t < H_MID * C_OUT) w2[t] = W2[t];
    int tile = blockIdx.x;
    if (t < 256) r[(t >> 4) * 17 + (t & 15)] = agg2[(size_t)tile * 256 + t];
    __syncthreads();
    int node = t / C_OUT, c = t % C_OUT;
    float acc = 0.f;
#pragma unroll
    for (int j = 0; j < H_MID; ++j) acc += r[node * 17 + j] * w2[j * C_OUT + c];
    out[(size_t)(tile * 16 + node) * C_OUT + c] = b2[c] + acc;
}

extern "C" void kernel_launch(void* const* d_in, const int* in_sizes, int n_in,
                              void* d_out, int out_size, void* d_ws, size_t ws_size,
                              hipStream_t stream) {
    const float* x  = (const float*)d_in[0];
    const int*   ei = (const int*)d_in[1];     // [2, E]: row 0 = src, row 1 = dst
    const float* W1 = (const float*)d_in[2];
    const float* b1 = (const float*)d_in[3];
    const float* W2 = (const float*)d_in[4];
    const float* b2 = (const float*)d_in[5];
    float* out = (float*)d_out;

    const int* src = ei;
    const int* dst = ei + N_EDGES;

    // ws (4B units): cnt[100352] | row_ptr[100352] | dinv[100352] |
    //                src_sorted[3.2M] | h1[1.6M] | agg1[1.6M] | agg2[1.6M]
    // cursor overlays agg2 (bucket finishes before agg2 is written). ~33.2 MB
    int*   cnt        = (int*)d_ws;
    int*   row_ptr    = cnt + 100352;
    float* dinv       = (float*)(row_ptr + 100352);
    int*   src_sorted = (int*)(dinv + 100352);
    float* h1         = (float*)(src_sorted + N_EDGES);
    float* agg1       = h1 + (size_t)N_NODES * H_MID;
    float* agg2       = agg1 + (size_t)N_NODES * H_MID;
    int*   cursor     = (int*)agg2;
    // scan partials: stash after agg2
    int*   part       = (int*)(agg2 + (size_t)N_NODES * H_MID);

    const int B = 256;
    k_zero  <<<(N_NODES + B - 1) / B, B, 0, stream>>>(cnt);
    k_count <<<(N_EDGES + B - 1) / B, B, 0, stream>>>(dst, cnt);
    k_dinv  <<<(N_NODES + B - 1) / B, B, 0, stream>>>(cnt, dinv);
    k_scan1 <<<SCAN_G, SCAN_B, 0, stream>>>(cnt, part);
    k_scan2 <<<1, 64, 0, stream>>>(part);
    k_scan3 <<<SCAN_G, SCAN_B, 0, stream>>>(cnt, part, row_ptr, cursor);
    k_bucket<<<(N_EDGES + B - 1) / B, B, 0, stream>>>(src, dst, cursor, src_sorted);
    k_gemm1 <<<N_NODES / 16, 256, 0, stream>>>(x, W1, h1);
    k_agg<false><<<N_NODES / 4, 256, 0, stream>>>(row_ptr, src_sorted, dinv, h1, b1, agg1);
    k_agg<true> <<<N_NODES / 4, 256, 0, stream>>>(row_ptr, src_sorted, dinv, agg1, b1, agg2);
    k_out   <<<N_NODES / 16, 640, 0, stream>>>(agg2, W2, b2, out);
}